// Round 7
// baseline (136.735 us; speedup 1.0000x reference)
//
#include <hip/hip_runtime.h>

#define ALPHA 0.2f

typedef __attribute__((ext_vector_type(2))) short short2v;
typedef __attribute__((ext_vector_type(4))) short short4v;
typedef __attribute__((ext_vector_type(8))) short short8v;
typedef __attribute__((ext_vector_type(4))) float f32x4;

__device__ __forceinline__ short f2bf(float f) {
  union { float f; unsigned u; } v; v.f = f;
  unsigned r = v.u + 0x7fffu + ((v.u >> 16) & 1u);   // RNE to bf16
  return (short)(r >> 16);
}

// ------------------------------------------------------------------
// K1: h = x@W  -> hT (bf16, [64][8192]);  s1 = h@a1, s2 = h@a2 (fp32)
// ------------------------------------------------------------------
__global__ __launch_bounds__(256) void k1_proj(
    const float* __restrict__ x, const float* __restrict__ W,
    const float* __restrict__ avec,
    short* __restrict__ hT, float* __restrict__ s1, float* __restrict__ s2) {
  __shared__ float xl[32 * 132];
  __shared__ float Wl[128 * 64];
  const int t   = threadIdx.x;
  const int rb  = blockIdx.x;
  const int row = t >> 3;
  const int fg  = t & 7;
  float acc[8];
#pragma unroll
  for (int e = 0; e < 8; e++) acc[e] = 0.f;

  for (int kc = 0; kc < 4; kc++) {
#pragma unroll
    for (int u = 0; u < 4; u++) {
      int lin = t + u * 256;
      int r = lin >> 5, c4 = lin & 31;
      float4 v = *(const float4*)(x + (size_t)(rb * 32 + r) * 512 + kc * 128 + c4 * 4);
      *(float4*)(xl + r * 132 + c4 * 4) = v;
    }
#pragma unroll
    for (int u = 0; u < 8; u++) {
      int lin = t + u * 256;
      int r = lin >> 4, c4 = lin & 15;
      float4 v = *(const float4*)(W + (size_t)(kc * 128 + r) * 64 + c4 * 4);
      *(float4*)(Wl + r * 64 + c4 * 4) = v;
    }
    __syncthreads();
#pragma unroll 8
    for (int k = 0; k < 128; k++) {
      float xv = xl[row * 132 + k];
      float4 w0 = *(const float4*)(Wl + k * 64 + fg * 8);
      float4 w1 = *(const float4*)(Wl + k * 64 + fg * 8 + 4);
      acc[0] = fmaf(xv, w0.x, acc[0]); acc[1] = fmaf(xv, w0.y, acc[1]);
      acc[2] = fmaf(xv, w0.z, acc[2]); acc[3] = fmaf(xv, w0.w, acc[3]);
      acc[4] = fmaf(xv, w1.x, acc[4]); acc[5] = fmaf(xv, w1.y, acc[5]);
      acc[6] = fmaf(xv, w1.z, acc[6]); acc[7] = fmaf(xv, w1.w, acc[7]);
    }
    __syncthreads();
  }

  float p1 = 0.f, p2 = 0.f;
#pragma unroll
  for (int e = 0; e < 8; e++) {
    p1 = fmaf(acc[e], avec[fg * 8 + e], p1);
    p2 = fmaf(acc[e], avec[64 + fg * 8 + e], p2);
  }
  p1 += __shfl_xor(p1, 1, 64); p1 += __shfl_xor(p1, 2, 64); p1 += __shfl_xor(p1, 4, 64);
  p2 += __shfl_xor(p2, 1, 64); p2 += __shfl_xor(p2, 2, 64); p2 += __shfl_xor(p2, 4, 64);
  const int gi = rb * 32 + row;
  if (fg == 0) { s1[gi] = p1; s2[gi] = p2; }
#pragma unroll
  for (int e = 0; e < 8; e++)
    hT[(size_t)(fg * 8 + e) * 8192 + gi] = f2bf(acc[e]);
}

// ------------------------------------------------------------------
// K1b: repack hT into MFMA-B-fragment order.
// hTt[((jb*4 + fb)*64 + l)*8 + e] = hT[(fb*16 + (l&15))*8192 + jb*32 + (l>>4)*8 + e]
// -> each B-fragment becomes one contiguous 1 KB wave-load.
// 65536 threads total (256 blocks x 256): one short8 per thread.
// ------------------------------------------------------------------
__global__ __launch_bounds__(256) void k1b_tile(
    const short* __restrict__ hT, short* __restrict__ hTt) {
  const int tid = blockIdx.x * 256 + threadIdx.x;   // 0..65535
  const int l  = tid & 63;
  const int fb = (tid >> 6) & 3;
  const int jb = tid >> 8;                          // 0..255
  const int lr = l & 15;
  const int lq = l >> 4;
  short8v v = *(const short8v*)(hT + (size_t)(fb * 16 + lr) * 8192 + jb * 32 + lq * 8);
  *(short8v*)(hTt + (size_t)tid * 8) = v;
}

// ------------------------------------------------------------------
// K2 v6: BARRIER-FREE fused kernel.
//  - B-frags: direct contiguous 1 KB wave-loads from pre-tiled hTt (L2).
//  - P tile: wave-private LDS (16x128 bf16, stride 136) -> no syncthreads.
//  - adj: 16 rows x 512 B contiguous per instr, depth-2 named ping/pong.
//  - chunk = 128 j-cols, nchunk = JSPAN/128.
// ------------------------------------------------------------------
__global__ __launch_bounds__(256, 4) void k2_attn(
    const float* __restrict__ adj, const short* __restrict__ hTt,
    const float* __restrict__ s1, const float* __restrict__ s2,
    float* __restrict__ num, float* __restrict__ den,
    const int KS, const int JSPAN) {
  __shared__ short Pl[4][16 * 136];   // wave-private 16x128 (+pad)
  const int t    = threadIdx.x;
  const int wvi  = t >> 6;
  const int l    = t & 63;
  const int lq   = l >> 4;            // 0..3
  const int lr   = l & 15;            // 0..15
  const int rb   = blockIdx.x & 127;
  const int ks   = blockIdx.x >> 7;
  const int r0   = rb << 6;
  const int j0   = ks * JSPAN;
  const int nchunk = JSPAN >> 7;      // pow2 (KS=8 -> 8)

  float s1r[16];
#pragma unroll
  for (int i = 0; i < 16; i++)
    s1r[i] = __int_as_float(
        __builtin_amdgcn_readfirstlane(__float_as_int(s1[r0 + wvi * 16 + i])));

  float denom_p[16];
#pragma unroll
  for (int i = 0; i < 16; i++) denom_p[i] = 0.f;

  f32x4 acc[4];
#pragma unroll
  for (int fb = 0; fb < 4; fb++) acc[fb] = (f32x4){0.f, 0.f, 0.f, 0.f};

  const float* arow0 = adj + (size_t)(r0 + wvi * 16) * 8192 + j0;
  const float* s2p   = s2 + j0;
  short* Pw = &Pl[wvi][0];

  float2 A0,A1,A2,A3,A4,A5,A6,A7,A8,A9,A10,A11,A12,A13,A14,A15;
  float2 B0,B1,B2,B3,B4,B5,B6,B7,B8,B9,B10,B11,B12,B13,B14,B15;
  float2 s2A, s2B;

#define LDADJ(S, JOFF) do { const float* ab__ = arow0 + (JOFF) + l * 2;       \
    S##0  = *(const float2*)(ab__);              S##1  = *(const float2*)(ab__ + 1 * 8192); \
    S##2  = *(const float2*)(ab__ + 2 * 8192);   S##3  = *(const float2*)(ab__ + 3 * 8192); \
    S##4  = *(const float2*)(ab__ + 4 * 8192);   S##5  = *(const float2*)(ab__ + 5 * 8192); \
    S##6  = *(const float2*)(ab__ + 6 * 8192);   S##7  = *(const float2*)(ab__ + 7 * 8192); \
    S##8  = *(const float2*)(ab__ + 8 * 8192);   S##9  = *(const float2*)(ab__ + 9 * 8192); \
    S##10 = *(const float2*)(ab__ + 10 * 8192);  S##11 = *(const float2*)(ab__ + 11 * 8192); \
    S##12 = *(const float2*)(ab__ + 12 * 8192);  S##13 = *(const float2*)(ab__ + 13 * 8192); \
    S##14 = *(const float2*)(ab__ + 14 * 8192);  S##15 = *(const float2*)(ab__ + 15 * 8192); \
  } while (0)

#define EXPROW(I, AV, S2V) do {                                               \
    float z0 = s1r[I] + S2V.x; z0 = fmaxf(z0, ALPHA * z0) * AV.x;             \
    float z1 = s1r[I] + S2V.y; z1 = fmaxf(z1, ALPHA * z1) * AV.y;             \
    float w0 = __expf(z0), w1 = __expf(z1);                                   \
    denom_p[I] += w0 + w1;                                                    \
    short2v pk = { f2bf(w0), f2bf(w1) };                                      \
    *(short2v*)(Pw + (I) * 136 + l * 2) = pk;                                 \
  } while (0)

#define K2_BODY(AS, S2, CIDX) do {                                           \
    EXPROW(0, AS##0, S2);   EXPROW(1, AS##1, S2);   EXPROW(2, AS##2, S2);    \
    EXPROW(3, AS##3, S2);   EXPROW(4, AS##4, S2);   EXPROW(5, AS##5, S2);    \
    EXPROW(6, AS##6, S2);   EXPROW(7, AS##7, S2);   EXPROW(8, AS##8, S2);    \
    EXPROW(9, AS##9, S2);   EXPROW(10, AS##10, S2); EXPROW(11, AS##11, S2);  \
    EXPROW(12, AS##12, S2); EXPROW(13, AS##13, S2); EXPROW(14, AS##14, S2);  \
    EXPROW(15, AS##15, S2);                                                  \
    { const int ja__ = (((CIDX) + 2) & (nchunk - 1)) * 128;                  \
      LDADJ(AS, ja__);                                                       \
      S2 = *(const float2*)(s2p + ja__ + l * 2); }                           \
    { const short* hb__ = hTt + ((size_t)((j0 >> 5) + (CIDX) * 4)) * 2048 +  \
                          (size_t)l * 8;                                     \
      _Pragma("unroll")                                                      \
      for (int kk = 0; kk < 4; kk++) {                                       \
        const short8v au = *(const short8v*)(Pw + lr * 136 + kk * 32 + lq * 8); \
        _Pragma("unroll")                                                    \
        for (int fb = 0; fb < 4; fb++) {                                     \
          const short8v bu = *(const short8v*)(hb__ + kk * 2048 + fb * 512); \
          acc[fb] = __builtin_amdgcn_mfma_f32_16x16x32_bf16(au, bu,          \
                                                            acc[fb], 0, 0, 0); \
        }                                                                    \
      }                                                                      \
    }                                                                        \
  } while (0)

  LDADJ(A, 0);   s2A = *(const float2*)(s2p + l * 2);
  LDADJ(B, 128); s2B = *(const float2*)(s2p + 128 + l * 2);

  for (int cc = 0; cc < nchunk; cc += 2) {
    K2_BODY(A, s2A, cc);
    K2_BODY(B, s2B, cc + 1);
  }
#undef LDADJ
#undef EXPROW
#undef K2_BODY

  // epilogue: partial denominators and numerators
#pragma unroll
  for (int i = 0; i < 16; i++) {
    float d = denom_p[i];
    d += __shfl_xor(d, 1, 64); d += __shfl_xor(d, 2, 64);
    d += __shfl_xor(d, 4, 64); d += __shfl_xor(d, 8, 64);
    d += __shfl_xor(d, 16, 64); d += __shfl_xor(d, 32, 64);
    if (l == 0) den[(size_t)ks * 8192 + r0 + wvi * 16 + i] = d;
  }
  float* np = num + (size_t)ks * 524288;
#pragma unroll
  for (int fb = 0; fb < 4; fb++)
#pragma unroll
    for (int r = 0; r < 4; r++)
      np[(size_t)(r0 + wvi * 16 + lq * 4 + r) * 64 + fb * 16 + lr] = acc[fb][r];
}

// ------------------------------------------------------------------
// K3: out = elu( sum_ks num / sum_ks den )
// ------------------------------------------------------------------
__global__ __launch_bounds__(256) void k3_norm(
    const float* __restrict__ num, const float* __restrict__ den,
    float* __restrict__ out, const int KS) {
  const int idx = blockIdx.x * 256 + threadIdx.x;   // 0..524287
  const int row = idx >> 6;
  float n = 0.f, d = 0.f;
  for (int ksi = 0; ksi < KS; ksi++) {
    n += num[(size_t)ksi * 524288 + idx];
    d += den[ksi * 8192 + row];
  }
  float v = n / d;
  out[idx] = v > 0.f ? v : (__expf(v) - 1.f);
}

extern "C" void kernel_launch(void* const* d_in, const int* in_sizes, int n_in,
                              void* d_out, int out_size, void* d_ws, size_t ws_size,
                              hipStream_t stream) {
  const float* x   = (const float*)d_in[0];
  const float* adj = (const float*)d_in[1];
  const float* W   = (const float*)d_in[2];
  const float* av  = (const float*)d_in[3];
  float* out = (float*)d_out;
  char* ws = (char*)d_ws;

  short* hT  = (short*)ws;                                 // 1 MB
  short* hTt = (short*)(ws + (1 << 20));                   // 1 MB (tiled)
  float* s1  = (float*)(ws + (2 << 20));                   // 32 KB
  float* s2  = (float*)(ws + (2 << 20) + 32768);           // 32 KB
  float* num = (float*)(ws + (2 << 20) + 65536);
  int KS = 8;
  while (KS > 1) {
    size_t need = (size_t)(2 << 20) + 65536 + (size_t)KS * (524288u * 4u + 32768u);
    if (need <= ws_size) break;
    KS >>= 1;
  }
  float* den = num + (size_t)KS * 524288;

  hipLaunchKernelGGL(k1_proj, dim3(256), dim3(256), 0, stream, x, W, av, hT, s1, s2);
  hipLaunchKernelGGL(k1b_tile, dim3(256), dim3(256), 0, stream, hT, hTt);
  hipLaunchKernelGGL(k2_attn, dim3(128 * KS), dim3(256), 0, stream,
                     adj, hTt, s1, s2, num, den, KS, 8192 / KS);
  hipLaunchKernelGGL(k3_norm, dim3(2048), dim3(256), 0, stream, num, den, out, KS);
}

// Round 8
// 100.197 us; speedup vs baseline: 1.3647x; 1.3647x over previous
//
#include <hip/hip_runtime.h>

#define ALPHA 0.2f

typedef __attribute__((ext_vector_type(2))) short short2v;
typedef __attribute__((ext_vector_type(8))) short short8v;
typedef __attribute__((ext_vector_type(4))) float f32x4;

__device__ __forceinline__ short f2bf(float f) {
  union { float f; unsigned u; } v; v.f = f;
  unsigned r = v.u + 0x7fffu + ((v.u >> 16) & 1u);   // RNE to bf16
  return (short)(r >> 16);
}

// ------------------------------------------------------------------
// K1: h = x@W  -> hT (bf16, [64][8192]);  s1 = h@a1, s2 = h@a2 (fp32)
// ------------------------------------------------------------------
__global__ __launch_bounds__(256) void k1_proj(
    const float* __restrict__ x, const float* __restrict__ W,
    const float* __restrict__ avec,
    short* __restrict__ hT, float* __restrict__ s1, float* __restrict__ s2) {
  __shared__ float xl[32 * 132];
  __shared__ float Wl[128 * 64];
  const int t   = threadIdx.x;
  const int rb  = blockIdx.x;
  const int row = t >> 3;
  const int fg  = t & 7;
  float acc[8];
#pragma unroll
  for (int e = 0; e < 8; e++) acc[e] = 0.f;

  for (int kc = 0; kc < 4; kc++) {
#pragma unroll
    for (int u = 0; u < 4; u++) {
      int lin = t + u * 256;
      int r = lin >> 5, c4 = lin & 31;
      float4 v = *(const float4*)(x + (size_t)(rb * 32 + r) * 512 + kc * 128 + c4 * 4);
      *(float4*)(xl + r * 132 + c4 * 4) = v;
    }
#pragma unroll
    for (int u = 0; u < 8; u++) {
      int lin = t + u * 256;
      int r = lin >> 4, c4 = lin & 15;
      float4 v = *(const float4*)(W + (size_t)(kc * 128 + r) * 64 + c4 * 4);
      *(float4*)(Wl + r * 64 + c4 * 4) = v;
    }
    __syncthreads();
#pragma unroll 8
    for (int k = 0; k < 128; k++) {
      float xv = xl[row * 132 + k];
      float4 w0 = *(const float4*)(Wl + k * 64 + fg * 8);
      float4 w1 = *(const float4*)(Wl + k * 64 + fg * 8 + 4);
      acc[0] = fmaf(xv, w0.x, acc[0]); acc[1] = fmaf(xv, w0.y, acc[1]);
      acc[2] = fmaf(xv, w0.z, acc[2]); acc[3] = fmaf(xv, w0.w, acc[3]);
      acc[4] = fmaf(xv, w1.x, acc[4]); acc[5] = fmaf(xv, w1.y, acc[5]);
      acc[6] = fmaf(xv, w1.z, acc[6]); acc[7] = fmaf(xv, w1.w, acc[7]);
    }
    __syncthreads();
  }

  float p1 = 0.f, p2 = 0.f;
#pragma unroll
  for (int e = 0; e < 8; e++) {
    p1 = fmaf(acc[e], avec[fg * 8 + e], p1);
    p2 = fmaf(acc[e], avec[64 + fg * 8 + e], p2);
  }
  p1 += __shfl_xor(p1, 1, 64); p1 += __shfl_xor(p1, 2, 64); p1 += __shfl_xor(p1, 4, 64);
  p2 += __shfl_xor(p2, 1, 64); p2 += __shfl_xor(p2, 2, 64); p2 += __shfl_xor(p2, 4, 64);
  const int gi = rb * 32 + row;
  if (fg == 0) { s1[gi] = p1; s2[gi] = p2; }
#pragma unroll
  for (int e = 0; e < 8; e++)
    hT[(size_t)(fg * 8 + e) * 8192 + gi] = f2bf(acc[e]);
}

// ------------------------------------------------------------------
// K2 v8: adj is the ONLY vmem stream in steady state.
//  - hT panel (64 f x 512 j, 64 KB) staged to LDS once; ONE barrier total.
//  - P wave-private LDS (16 KB). Both XOR-swizzled ((row&7)<<4): 2-way max.
//  - MFMA A/B frags via ds_read_b128 (lgkmcnt) -> adj vmcnt queue never
//    ordered behind anything, never drained.
//  - adj: 16 rows x 512 B contiguous per instr, depth-2 named ping/pong,
//    per-wave chunk stagger (cc+wvi)&3 for channel spread.
//  - KS=16 j-splits; grid 128x16=2048 blocks; LDS 80 KB -> 2 blocks/CU.
// ------------------------------------------------------------------
__global__ __launch_bounds__(256, 2) void k2_attn(
    const float* __restrict__ adj, const short* __restrict__ hT,
    const float* __restrict__ s1, const float* __restrict__ s2,
    float* __restrict__ num, float* __restrict__ den) {
  __shared__ short hP[32768];        // 64 KB: [f=64][col=512], stride 1024 B, swizzled
  __shared__ short Pl[8192];         // 16 KB: 4 waves x [16][128], swizzled
  const int t    = threadIdx.x;
  const int wvi  = t >> 6;
  const int l    = t & 63;
  const int lq   = l >> 4;           // 0..3
  const int lr   = l & 15;           // 0..15
  const int rb   = blockIdx.x & 127;
  const int ks   = blockIdx.x >> 7;
  const int r0   = rb << 6;
  const int j0   = ks << 9;          // JSPAN = 512

  // ---- stage hT panel: 16 rounds x 256 thr x 16 B (pre-swizzled source)
#pragma unroll
  for (int r = 0; r < 16; r++) {
    const int d    = r * 4096 + t * 16;            // dest byte in panel
    const int frow = d >> 10;
    const int lcb  = (d & 1023) ^ ((frow & 7) << 4);  // logical col-byte
    short8v v = *(const short8v*)(hT + (size_t)frow * 8192 + j0 + (lcb >> 1));
    *(short8v*)((char*)hP + d) = v;
  }
  __syncthreads();                   // the only barrier

  float s1r[16];
#pragma unroll
  for (int i = 0; i < 16; i++)
    s1r[i] = __int_as_float(
        __builtin_amdgcn_readfirstlane(__float_as_int(s1[r0 + wvi * 16 + i])));

  float denom_p[16];
#pragma unroll
  for (int i = 0; i < 16; i++) denom_p[i] = 0.f;

  f32x4 acc[4];
#pragma unroll
  for (int fb = 0; fb < 4; fb++) acc[fb] = (f32x4){0.f, 0.f, 0.f, 0.f};

  const float* arow0 = adj + (size_t)(r0 + wvi * 16) * 8192 + j0;
  const float* s2p   = s2 + j0;
  char* Pw = (char*)Pl + wvi * 4096;

  // wave-staggered chunk order: c_w(k) = (wvi + k) & 3
  const int c0 = wvi & 3, c1 = (wvi + 1) & 3, c2 = (wvi + 2) & 3, c3 = (wvi + 3) & 3;

  float2 A0,A1,A2,A3,A4,A5,A6,A7,A8,A9,A10,A11,A12,A13,A14,A15;
  float2 B0,B1,B2,B3,B4,B5,B6,B7,B8,B9,B10,B11,B12,B13,B14,B15;
  float2 s2A, s2B;

#define LDADJ(S, CL) do { const float* ab__ = arow0 + (CL) * 128 + l * 2;     \
    S##0  = *(const float2*)(ab__);              S##1  = *(const float2*)(ab__ + 1 * 8192); \
    S##2  = *(const float2*)(ab__ + 2 * 8192);   S##3  = *(const float2*)(ab__ + 3 * 8192); \
    S##4  = *(const float2*)(ab__ + 4 * 8192);   S##5  = *(const float2*)(ab__ + 5 * 8192); \
    S##6  = *(const float2*)(ab__ + 6 * 8192);   S##7  = *(const float2*)(ab__ + 7 * 8192); \
    S##8  = *(const float2*)(ab__ + 8 * 8192);   S##9  = *(const float2*)(ab__ + 9 * 8192); \
    S##10 = *(const float2*)(ab__ + 10 * 8192);  S##11 = *(const float2*)(ab__ + 11 * 8192); \
    S##12 = *(const float2*)(ab__ + 12 * 8192);  S##13 = *(const float2*)(ab__ + 13 * 8192); \
    S##14 = *(const float2*)(ab__ + 14 * 8192);  S##15 = *(const float2*)(ab__ + 15 * 8192); \
  } while (0)

#define EXPROW(I, AV, S2V) do {                                               \
    float z0 = s1r[I] + S2V.x; z0 = fmaxf(z0, ALPHA * z0) * AV.x;             \
    float z1 = s1r[I] + S2V.y; z1 = fmaxf(z1, ALPHA * z1) * AV.y;             \
    float w0 = __expf(z0), w1 = __expf(z1);                                   \
    denom_p[I] += w0 + w1;                                                    \
    short2v pk = { f2bf(w0), f2bf(w1) };                                      \
    *(short2v*)(Pw + ((((I) << 8) + (l << 2)) ^ (((I) & 7) << 4))) = pk;      \
  } while (0)

#define K2_BODY(AS, S2, CL, PREF, CP) do {                                    \
    EXPROW(0, AS##0, S2);   EXPROW(1, AS##1, S2);   EXPROW(2, AS##2, S2);     \
    EXPROW(3, AS##3, S2);   EXPROW(4, AS##4, S2);   EXPROW(5, AS##5, S2);     \
    EXPROW(6, AS##6, S2);   EXPROW(7, AS##7, S2);   EXPROW(8, AS##8, S2);     \
    EXPROW(9, AS##9, S2);   EXPROW(10, AS##10, S2); EXPROW(11, AS##11, S2);   \
    EXPROW(12, AS##12, S2); EXPROW(13, AS##13, S2); EXPROW(14, AS##14, S2);   \
    EXPROW(15, AS##15, S2);                                                   \
    if (PREF) { LDADJ(AS, CP); S2 = *(const float2*)(s2p + (CP) * 128 + l * 2); } \
    _Pragma("unroll")                                                         \
    for (int kk = 0; kk < 4; kk++) {                                          \
      const int ab__ = ((lr << 8) + (kk << 6) + (lq << 4)) ^ ((lr & 7) << 4); \
      const short8v au = *(const short8v*)(Pw + ab__);                        \
      _Pragma("unroll")                                                       \
      for (int fb = 0; fb < 4; fb++) {                                        \
        const int fr__ = fb * 16 + lr;                                        \
        const int bb__ = ((fr__ << 10) + (((CL) << 8) + (kk << 6) + (lq << 4))) \
                         ^ ((fr__ & 7) << 4);                                 \
        const short8v bu = *(const short8v*)((char*)hP + bb__);               \
        acc[fb] = __builtin_amdgcn_mfma_f32_16x16x32_bf16(au, bu,             \
                                                          acc[fb], 0, 0, 0); \
      }                                                                       \
    }                                                                         \
  } while (0)

  LDADJ(A, c0); s2A = *(const float2*)(s2p + c0 * 128 + l * 2);
  LDADJ(B, c1); s2B = *(const float2*)(s2p + c1 * 128 + l * 2);

  K2_BODY(A, s2A, c0, 1, c2);
  K2_BODY(B, s2B, c1, 1, c3);
  K2_BODY(A, s2A, c2, 0, 0);
  K2_BODY(B, s2B, c3, 0, 0);
#undef LDADJ
#undef EXPROW
#undef K2_BODY

  // epilogue: partial denominators and numerators
#pragma unroll
  for (int i = 0; i < 16; i++) {
    float d = denom_p[i];
    d += __shfl_xor(d, 1, 64); d += __shfl_xor(d, 2, 64);
    d += __shfl_xor(d, 4, 64); d += __shfl_xor(d, 8, 64);
    d += __shfl_xor(d, 16, 64); d += __shfl_xor(d, 32, 64);
    if (l == 0) den[(size_t)ks * 8192 + r0 + wvi * 16 + i] = d;
  }
  float* np = num + (size_t)ks * 524288;
#pragma unroll
  for (int fb = 0; fb < 4; fb++)
#pragma unroll
    for (int r = 0; r < 4; r++)
      np[(size_t)(r0 + wvi * 16 + lq * 4 + r) * 64 + fb * 16 + lr] = acc[fb][r];
}

// ------------------------------------------------------------------
// K3: out = elu( sum_ks num / sum_ks den ),  KS = 16
// ------------------------------------------------------------------
__global__ __launch_bounds__(256) void k3_norm(
    const float* __restrict__ num, const float* __restrict__ den,
    float* __restrict__ out) {
  const int idx = blockIdx.x * 256 + threadIdx.x;   // 0..524287
  const int row = idx >> 6;
  float n = 0.f, d = 0.f;
#pragma unroll
  for (int ksi = 0; ksi < 16; ksi++) {
    n += num[(size_t)ksi * 524288 + idx];
    d += den[ksi * 8192 + row];
  }
  float v = n / d;
  out[idx] = v > 0.f ? v : (__expf(v) - 1.f);
}

extern "C" void kernel_launch(void* const* d_in, const int* in_sizes, int n_in,
                              void* d_out, int out_size, void* d_ws, size_t ws_size,
                              hipStream_t stream) {
  const float* x   = (const float*)d_in[0];
  const float* adj = (const float*)d_in[1];
  const float* W   = (const float*)d_in[2];
  const float* av  = (const float*)d_in[3];
  float* out = (float*)d_out;
  char* ws = (char*)d_ws;

  short* hT  = (short*)ws;                                 // 1 MB
  float* s1  = (float*)(ws + (1 << 20));                   // 32 KB
  float* s2  = (float*)(ws + (1 << 20) + 32768);           // 32 KB
  float* num = (float*)(ws + (1 << 20) + 65536);           // 16 x 2 MB
  float* den = num + 16u * 524288u;                        // 16 x 32 KB

  hipLaunchKernelGGL(k1_proj, dim3(256), dim3(256), 0, stream, x, W, av, hT, s1, s2);
  hipLaunchKernelGGL(k2_attn, dim3(2048), dim3(256), 0, stream,
                     adj, hT, s1, s2, num, den);
  hipLaunchKernelGGL(k3_norm, dim3(2048), dim3(256), 0, stream, num, den, out);
}